// Round 4
// baseline (164.343 us; speedup 1.0000x reference)
//
#include <hip/hip_runtime.h>

// LambdaLoss: B=4096 lists, L=128 items.
// per list: sum over pairs rel_i > rel_j of |rd| * softplus(-(p_i - p_j)),
// divided by valid-pair count; output = mean over lists with >=1 valid pair.
//
// Kernel 1: one block per list. Triangular pair enumeration via circular
// offsets (i, (i+d)&127), d=1..64 (d=64 masked to i<64).
//  - Per-pair exp ELIMINATED: E_k = exp2(p_k*log2e), R_k = 1/E_k precomputed
//    per row; exp2(-(p_win - p_lose)) = E_lose * R_win via two cndmasks.
//  - LDS holds mirrored float4 (E, R, r, 0): one ds_read_b128 per pair, no
//    wrap mask (addresses fold into immediates).
//  - softplus = ln2 * log2(1 + e); ln2 folded into the final division.
//  - valid-pair count via 5-bin relevance histogram:
//    cnt = C(128,2) - sum C(c_v,2).
//  - Block results accumulated with non-returning global atomicAdd into
//    ws[0..1] (zeroed by an 8-byte hipMemsetAsync).
// Kernel 2: single wave does the final division.

#define LB 4096
#define LLEN 128

#define EXP2F(x) __builtin_amdgcn_exp2f(x)   // v_exp_f32 (2^x)
#define LOG2F(x) __builtin_amdgcn_logf(x)    // v_log_f32 (log2)
#define RCPF(x)  __builtin_amdgcn_rcpf(x)    // v_rcp_f32

__global__ __launch_bounds__(256) void lambda_pairs_kernel(
    const float* __restrict__ pred, const float* __restrict__ rel,
    float* __restrict__ gaccum) {
  __shared__ float4 s[2 * LLEN];   // mirrored: s[k] == s[k+128]
  __shared__ int hist[8];
  __shared__ float wsum[4];

  const int t = threadIdx.x;
  const int b = blockIdx.x;
  const int i = t & (LLEN - 1);

  constexpr float LOG2E = 1.4426950408889634f;
  constexpr float LN2   = 0.6931471805599453f;

  // stage: every thread computes its row's (E, R, r); upper half re-reads (L1 hit)
  const float pi = pred[b * LLEN + i];
  const float ri = rel[b * LLEN + i];
  const float Ei = EXP2F(pi * LOG2E);
  const float Ri = RCPF(Ei);
  s[t] = make_float4(Ei, Ri, ri, 0.f);
  if (t < 8) hist[t] = 0;
  __syncthreads();
  if (t < LLEN) atomicAdd(&hist[(int)ri], 1);

  // thread half selects odd (d=1,3,..,63) or even (d=2,4,..,64) offsets
  const int j0 = i + 1 + (t >> 7);   // max addr: 129 + 62 = 191 < 256
  float acc = 0.f;

#pragma unroll 4
  for (int k = 0; k < 31; ++k) {
    float4 v  = s[j0 + 2 * k];
    float  rd = ri - v.z;
    // e = exp2(-(p_win - p_lose)) = E_lose * R_win
    float  a  = (rd > 0.f) ? v.x : Ei;   // E of loser
    float  r  = (rd > 0.f) ? Ri  : v.y;  // R of winner
    float  lg = LOG2F(fmaf(a, r, 1.f));
    acc = fmaf(fabsf(rd), lg, acc);      // |rd|=0 for ties -> no-op
  }
  { // tail: d=63 (lower half, all i) or d=64 (upper half, only i<64)
    float4 v  = s[j0 + 62];
    float  rd = ri - v.z;
    float  w  = ((t < 128) || (i < 64)) ? fabsf(rd) : 0.f;
    float  a  = (rd > 0.f) ? v.x : Ei;
    float  r  = (rd > 0.f) ? Ri  : v.y;
    float  lg = LOG2F(fmaf(a, r, 1.f));
    acc = fmaf(w, lg, acc);
  }

  // wave (64-lane) shuffle reduction, then cross-wave via LDS
  for (int off = 32; off > 0; off >>= 1) acc += __shfl_down(acc, off, 64);
  if ((t & 63) == 0) wsum[t >> 6] = acc;
  __syncthreads();
  if (t == 0) {
    float ssum = (wsum[0] + wsum[1]) + (wsum[2] + wsum[3]);
    int same = 0;
#pragma unroll
    for (int v = 0; v < 5; ++v) same += hist[v] * (hist[v] - 1) / 2;
    const int cnt = (LLEN * (LLEN - 1) / 2) - same;
    if (cnt > 0) {
      atomicAdd(&gaccum[0], (LN2 * ssum) / (float)cnt);  // sum of per-list losses
      atomicAdd(&gaccum[1], 1.f);                        // number of valid lists
    }
  }
}

__global__ __launch_bounds__(64) void lambda_finalize_kernel(
    const float* __restrict__ gaccum, float* __restrict__ out) {
  if (threadIdx.x == 0) {
    float s = gaccum[0], n = gaccum[1];
    out[0] = (n > 0.f) ? s / n : 0.f;
  }
}

extern "C" void kernel_launch(void* const* d_in, const int* in_sizes, int n_in,
                              void* d_out, int out_size, void* d_ws, size_t ws_size,
                              hipStream_t stream) {
  const float* pred = (const float*)d_in[0];
  const float* rel  = (const float*)d_in[1];
  float* out    = (float*)d_out;
  float* gaccum = (float*)d_ws;   // [2]: loss-sum, valid-count

  hipMemsetAsync(gaccum, 0, 2 * sizeof(float), stream);
  lambda_pairs_kernel<<<dim3(LB), dim3(256), 0, stream>>>(pred, rel, gaccum);
  lambda_finalize_kernel<<<dim3(1), dim3(64), 0, stream>>>(gaccum, out);
}

// Round 5
// 66.954 us; speedup vs baseline: 2.4546x; 2.4546x over previous
//
#include <hip/hip_runtime.h>

// LambdaLoss: B=4096 lists, L=128 items.
// per list: sum over pairs rel_i > rel_j of |rd| * softplus(-(p_i - p_j)),
// divided by valid-pair count; output = mean over lists with >=1 valid pair.
//
// Kernel 1: one block per list. Triangular pair enumeration via circular
// offsets (i, (i+d)&127), d=1..64 (d=64 masked to i<64).
//  - Per-pair exp eliminated: E_k = exp2(p_k*log2e), R_k = 1/E_k per row;
//    exp(-(p_win - p_lose)) = E_lose * R_win via two cndmasks.
//  - LDS: three stride-1 float arrays (mirrored, 192 entries) -> lane stride
//    4 B = 2-way bank aliasing = free; E/R 192 dwords apart (ds_read2-able).
//    NO global atomics (R4 lesson: 8192 same-address atomics serialized
//    ~100 us at the coherence point). Per-list float2 store instead.
//  - softplus = ln2 * log2(1 + e); ln2 folded into per-list division.
//  - valid-pair count via 5-bin relevance histogram:
//    cnt = C(128,2) - sum C(c_v,2).
// Kernel 2: single block, coalesced float4 reduction of the 4096 float2.

#define LB 4096
#define LLEN 128
#define MIR 192   // mirrored length: max index 129 + 62 = 191

#define EXP2F(x) __builtin_amdgcn_exp2f(x)   // v_exp_f32 (2^x)
#define LOG2F(x) __builtin_amdgcn_logf(x)    // v_log_f32 (log2)
#define RCPF(x)  __builtin_amdgcn_rcpf(x)    // v_rcp_f32

__global__ __launch_bounds__(256) void lambda_pairs_kernel(
    const float* __restrict__ pred, const float* __restrict__ rel,
    float2* __restrict__ per2) {
  __shared__ float sE[MIR];
  __shared__ float sR[MIR];
  __shared__ float sr[MIR];
  __shared__ int hist[8];
  __shared__ float wsum[4];

  const int t = threadIdx.x;
  const int b = blockIdx.x;
  const int i = t & (LLEN - 1);

  constexpr float LOG2E = 1.4426950408889634f;
  constexpr float LN2   = 0.6931471805599453f;

  // stage: every thread computes its row's (E, R, r); t in [128,192) mirrors
  const float pi = pred[b * LLEN + i];
  const float ri = rel[b * LLEN + i];
  const float Ei = EXP2F(pi * LOG2E);
  const float Ri = RCPF(Ei);
  if (t < MIR) { sE[t] = Ei; sR[t] = Ri; sr[t] = ri; }
  if (t < 8) hist[t] = 0;
  __syncthreads();
  if (t < LLEN) atomicAdd(&hist[(int)ri], 1);

  // thread half selects odd (d=1,3,..,63) or even (d=2,4,..,64) offsets
  const int j0 = i + 1 + (t >> 7);   // max addr: 129 + 62 = 191
  float acc = 0.f;

#pragma unroll 8
  for (int k = 0; k < 31; ++k) {
    const int j = j0 + 2 * k;
    float rj = sr[j];
    float Ej = sE[j];
    float Rj = sR[j];
    float rd = ri - rj;
    // e = exp(-(p_win - p_lose)) = E_lose * R_win
    float a  = (rd > 0.f) ? Ej : Ei;   // E of loser
    float r  = (rd > 0.f) ? Ri : Rj;   // R of winner
    float lg = LOG2F(fmaf(a, r, 1.f));
    acc = fmaf(fabsf(rd), lg, acc);    // |rd|=0 for ties -> no-op
  }
  { // tail: d=63 (lower half, all i) or d=64 (upper half, only i<64)
    const int j = j0 + 62;
    float rj = sr[j];
    float Ej = sE[j];
    float Rj = sR[j];
    float rd = ri - rj;
    float w  = ((t < 128) || (i < 64)) ? fabsf(rd) : 0.f;
    float a  = (rd > 0.f) ? Ej : Ei;
    float r  = (rd > 0.f) ? Ri : Rj;
    float lg = LOG2F(fmaf(a, r, 1.f));
    acc = fmaf(w, lg, acc);
  }

  // wave (64-lane) shuffle reduction, then cross-wave via LDS
  for (int off = 32; off > 0; off >>= 1) acc += __shfl_down(acc, off, 64);
  if ((t & 63) == 0) wsum[t >> 6] = acc;
  __syncthreads();
  if (t == 0) {
    float ssum = (wsum[0] + wsum[1]) + (wsum[2] + wsum[3]);
    int same = 0;
#pragma unroll
    for (int v = 0; v < 5; ++v) same += hist[v] * (hist[v] - 1) / 2;
    const int cnt = (LLEN * (LLEN - 1) / 2) - same;
    per2[b] = make_float2((cnt > 0) ? (LN2 * ssum) / (float)cnt : 0.f,
                          (cnt > 0) ? 1.f : 0.f);
  }
}

__global__ __launch_bounds__(256) void lambda_finalize_kernel(
    const float2* __restrict__ per2, float* __restrict__ out) {
  __shared__ float wsum[4], wcnt[4];
  const int t = threadIdx.x;
  const float4* v = (const float4*)per2;   // 4096 float2 = 2048 float4
  float s = 0.f, n = 0.f;
#pragma unroll
  for (int idx = t; idx < 2048; idx += 256) {
    float4 q = v[idx];
    s += q.x + q.z;
    n += q.y + q.w;
  }
  for (int off = 32; off > 0; off >>= 1) {
    s += __shfl_down(s, off, 64);
    n += __shfl_down(n, off, 64);
  }
  if ((t & 63) == 0) { wsum[t >> 6] = s; wcnt[t >> 6] = n; }
  __syncthreads();
  if (t == 0) {
    float ts = (wsum[0] + wsum[1]) + (wsum[2] + wsum[3]);
    float tn = (wcnt[0] + wcnt[1]) + (wcnt[2] + wcnt[3]);
    out[0] = (tn > 0.f) ? ts / tn : 0.f;
  }
}

extern "C" void kernel_launch(void* const* d_in, const int* in_sizes, int n_in,
                              void* d_out, int out_size, void* d_ws, size_t ws_size,
                              hipStream_t stream) {
  const float* pred = (const float*)d_in[0];
  const float* rel  = (const float*)d_in[1];
  float* out   = (float*)d_out;
  float2* per2 = (float2*)d_ws;   // [4096] (ratio, valid)

  lambda_pairs_kernel<<<dim3(LB), dim3(256), 0, stream>>>(pred, rel, per2);
  lambda_finalize_kernel<<<dim3(1), dim3(256), 0, stream>>>(per2, out);
}

// Round 6
// 64.758 us; speedup vs baseline: 2.5378x; 1.0339x over previous
//
#include <hip/hip_runtime.h>

// LambdaLoss: B=4096 lists, L=128 items.
// per list: sum over pairs rel_i > rel_j of |rd| * softplus(-(p_i - p_j)),
// divided by valid-pair count; output = mean over lists with >=1 valid pair.
//
// Key decomposition (R6): with E_k = exp2(p_k*log2e), y_k = p_k*log2e:
//   softplus(-(p_w - p_l)) = ln2 * (log2(E_i + E_j) - y_w)
// and the winner-y part is separable via the relevance histogram:
//   sum_pairs |rd|*y_w = sum_i y_i * W_i,  W_i = sum_v c_v * relu(r_i - v)
// so the per-pair loop needs only (E_j, r_j) -> ONE ds_read_b64 (float2)
// and 4 VALU ops (sub, add, v_log, fma). LDS pipe ~6 cyc/iter (was ~11.6).
//
// Kernel 1: one block per list, triangular pairs via circular offsets
// (i, i+d), d=1..64 (d=64 masked to i<64), mirrored LDS (no wrap mask).
// Per-list result stored to ws (NO global atomics - R4 lesson: same-address
// atomics from 4096 blocks serialized ~100us).
// Kernel 2: single block, coalesced float4 reduction of 4096 float2.

#define LB 4096
#define LLEN 128
#define MIR 192   // mirrored length: max index 129 + 62 = 191

#define EXP2F(x) __builtin_amdgcn_exp2f(x)   // v_exp_f32 (2^x)
#define LOG2F(x) __builtin_amdgcn_logf(x)    // v_log_f32 (log2)

__global__ __launch_bounds__(256) void lambda_pairs_kernel(
    const float* __restrict__ pred, const float* __restrict__ rel,
    float2* __restrict__ per2) {
  __shared__ float2 s2[MIR];      // (E, r), mirrored
  __shared__ int hist[8];
  __shared__ float wsum[4];

  const int t = threadIdx.x;
  const int b = blockIdx.x;
  const int i = t & (LLEN - 1);

  constexpr float LOG2E = 1.4426950408889634f;
  constexpr float LN2   = 0.6931471805599453f;

  // stage: every thread computes its row's (E, r); t in [128,192) mirrors
  const float pi = pred[b * LLEN + i];
  const float ri = rel[b * LLEN + i];
  const float yi = pi * LOG2E;
  const float Ei = EXP2F(yi);
  if (t < 8) hist[t] = 0;
  if (t < MIR) s2[t] = make_float2(Ei, ri);
  __syncthreads();
  if (t < LLEN) atomicAdd(&hist[(int)ri], 1);
  __syncthreads();   // hist and s2 both ready

  // thread half selects odd (d=1,3,..,63) or even (d=2,4,..,64) offsets
  const int j0 = i + 1 + (t >> 7);   // max addr: 129 + 62 = 191
  float acc = 0.f;

#pragma unroll 8
  for (int k = 0; k < 31; ++k) {
    float2 v  = s2[j0 + 2 * k];
    float  rd = ri - v.y;
    float  lg = LOG2F(Ei + v.x);
    acc = fmaf(fabsf(rd), lg, acc);    // |rd|=0 for ties -> no-op
  }
  { // tail: d=63 (lower half, all i) or d=64 (upper half, only i<64)
    float2 v  = s2[j0 + 62];
    float  rd = ri - v.y;
    float  w  = ((t < 128) || (i < 64)) ? fabsf(rd) : 0.f;
    acc = fmaf(w, LOG2F(Ei + v.x), acc);
  }

  // per-row winner-y correction: acc -= y_i * W_i (only one thread per row)
  if (t < LLEN) {
    float W = 0.f;
#pragma unroll
    for (int v = 0; v < 5; ++v) {
      float d = ri - (float)v;
      W = fmaf((float)hist[v], fmaxf(d, 0.f), W);
    }
    acc = fmaf(-yi, W, acc);
  }

  // wave (64-lane) shuffle reduction, then cross-wave via LDS
  for (int off = 32; off > 0; off >>= 1) acc += __shfl_down(acc, off, 64);
  if ((t & 63) == 0) wsum[t >> 6] = acc;
  __syncthreads();
  if (t == 0) {
    float ssum = (wsum[0] + wsum[1]) + (wsum[2] + wsum[3]);
    int same = 0;
#pragma unroll
    for (int v = 0; v < 5; ++v) same += hist[v] * (hist[v] - 1) / 2;
    const int cnt = (LLEN * (LLEN - 1) / 2) - same;
    per2[b] = make_float2((cnt > 0) ? (LN2 * ssum) / (float)cnt : 0.f,
                          (cnt > 0) ? 1.f : 0.f);
  }
}

__global__ __launch_bounds__(256) void lambda_finalize_kernel(
    const float2* __restrict__ per2, float* __restrict__ out) {
  __shared__ float wsum[4], wcnt[4];
  const int t = threadIdx.x;
  const float4* v = (const float4*)per2;   // 4096 float2 = 2048 float4
  float s = 0.f, n = 0.f;
#pragma unroll
  for (int idx = t; idx < 2048; idx += 256) {
    float4 q = v[idx];
    s += q.x + q.z;
    n += q.y + q.w;
  }
  for (int off = 32; off > 0; off >>= 1) {
    s += __shfl_down(s, off, 64);
    n += __shfl_down(n, off, 64);
  }
  if ((t & 63) == 0) { wsum[t >> 6] = s; wcnt[t >> 6] = n; }
  __syncthreads();
  if (t == 0) {
    float ts = (wsum[0] + wsum[1]) + (wsum[2] + wsum[3]);
    float tn = (wcnt[0] + wcnt[1]) + (wcnt[2] + wcnt[3]);
    out[0] = (tn > 0.f) ? ts / tn : 0.f;
  }
}

extern "C" void kernel_launch(void* const* d_in, const int* in_sizes, int n_in,
                              void* d_out, int out_size, void* d_ws, size_t ws_size,
                              hipStream_t stream) {
  const float* pred = (const float*)d_in[0];
  const float* rel  = (const float*)d_in[1];
  float* out   = (float*)d_out;
  float2* per2 = (float2*)d_ws;   // [4096] (ratio, valid)

  lambda_pairs_kernel<<<dim3(LB), dim3(256), 0, stream>>>(pred, rel, per2);
  lambda_finalize_kernel<<<dim3(1), dim3(256), 0, stream>>>(per2, out);
}